// Round 4
// baseline (390.678 us; speedup 1.0000x reference)
//
#include <hip/hip_runtime.h>
#include <hip/hip_bf16.h>
#include <stdint.h>

typedef unsigned long long u64;
typedef unsigned int u32;
typedef __attribute__((ext_vector_type(8))) short bf16x8;
typedef __attribute__((ext_vector_type(8))) unsigned short u16x8;
typedef __attribute__((ext_vector_type(4))) float f32x4;

__device__ __forceinline__ float ldv(const void* p, size_t idx, int mode) {
  return mode ? __bfloat162float(((const __hip_bfloat16*)p)[idx])
              : ((const float*)p)[idx];
}
__device__ __forceinline__ void stv(void* p, size_t idx, int mode, float v) {
  if (mode) ((__hip_bfloat16*)p)[idx] = __float2bfloat16(v);
  else      ((float*)p)[idx] = v;
}
__device__ __forceinline__ unsigned short f2bfb(float f) {  // RNE f32->bf16 bits
  u32 u = __float_as_uint(f);
  u32 r = u + 0x7fffu + ((u >> 16) & 1u);
  return (unsigned short)(r >> 16);
}
__device__ __forceinline__ float bfb2f(unsigned short b) {
  return __uint_as_float((u32)b << 16);
}
__device__ __forceinline__ u64 shflxor64(u64 v, int m) {
  int lo = __shfl_xor((int)(u32)(v & 0xffffffffu), m, 64);
  int hi = __shfl_xor((int)(u32)(v >> 32), m, 64);
  return ((u64)(u32)hi << 32) | (u32)lo;
}

// monotonic float<->uint encoding for atomicMin/Max-based bbox
__device__ __forceinline__ u32 benc(float f) {
  u32 u = __float_as_uint(f);
  return (u & 0x80000000u) ? ~u : (u | 0x80000000u);
}
__device__ __forceinline__ float bdec(u32 k) {
  return (k & 0x80000000u) ? __uint_as_float(k ^ 0x80000000u)
                           : __uint_as_float(~k);
}

// full ascending 64-lane bitonic sort of u64 keys (exact lax.top_k order)
__device__ __forceinline__ u64 sort64(u64 cand, int lane) {
#pragma unroll
  for (int k = 2; k <= 64; k <<= 1) {
#pragma unroll
    for (int j = k >> 1; j > 0; j >>= 1) {
      u64 other = shflxor64(cand, j);
      bool up    = ((lane & k) == 0) || (k == 64);
      bool lower = ((lane & j) == 0);
      bool keepMin = (up == lower);
      u64 mn = cand < other ? cand : other;
      u64 mx = cand < other ? other : cand;
      cand = keepMin ? mn : mx;
    }
  }
  return cand;
}

__global__ void PointNetSimple_61409442398998_kernel() {}

// ---------------------------------------------------------------------------
// setup: dtype-detect + weight transpose/convert + vector cvt + prep.
// Prep branch also contributes bbox atomics (bbx pre-init'd by hipMemsetAsync).
// ---------------------------------------------------------------------------
struct CvtEnt { const void* src; float* dst; int n; };
struct CvtArgs { CvtEnt e[12]; };
struct WEnt { const void* src; unsigned short* dst; int K, N, Kpad; };
struct WArgs { WEnt e[6]; };

__global__ void setup_kernel(const void* __restrict__ pos,
                             const void* __restrict__ nrm,
                             WArgs wa, CvtArgs ca,
                             int* __restrict__ flag,
                             float4* __restrict__ pos4,
                             float* __restrict__ h0, int n) {
  const unsigned short* u16p = (const unsigned short*)pos;
  int cnt = 0;
  for (int k = 0; k < 32; ++k) {
    int e = (u16p[k] >> 7) & 0xff;
    if (e >= 110 && e <= 140) cnt++;
  }
  const int mode = (cnt >= 26) ? 1 : 0;

  const int nprep = n >> 8;
  const int b = blockIdx.x;
  if (b < nprep) {
    int i = b * 256 + threadIdx.x;
    float x = ldv(pos, 3*(size_t)i+0, mode);
    float y = ldv(pos, 3*(size_t)i+1, mode);
    float z = ldv(pos, 3*(size_t)i+2, mode);
    pos4[i] = make_float4(x, y, z, x*x + y*y + z*z);
    h0[6*(size_t)i+0] = x; h0[6*(size_t)i+1] = y; h0[6*(size_t)i+2] = z;
    h0[6*(size_t)i+3] = ldv(nrm, 3*(size_t)i+0, mode);
    h0[6*(size_t)i+4] = ldv(nrm, 3*(size_t)i+1, mode);
    h0[6*(size_t)i+5] = ldv(nrm, 3*(size_t)i+2, mode);
    // bbox contribution (bbx = ((u32*)flag)+4..9, init'd by memset)
    float bmn[3] = {x, y, z}, bmx[3] = {x, y, z};
#pragma unroll
    for (int m = 32; m; m >>= 1) {
#pragma unroll
      for (int k = 0; k < 3; ++k) {
        bmn[k] = fminf(bmn[k], __shfl_xor(bmn[k], m, 64));
        bmx[k] = fmaxf(bmx[k], __shfl_xor(bmx[k], m, 64));
      }
    }
    if ((threadIdx.x & 63) == 0) {
      u32* bb = (u32*)flag;
#pragma unroll
      for (int k = 0; k < 3; ++k) {
        atomicMin(&bb[4 + k], benc(bmn[k]));
        atomicMax(&bb[7 + k], benc(bmx[k]));
      }
    }
  } else {
    int r = b - nprep;
    if (r < 6) {
      WEnt ent = wa.e[r];
      for (int t = threadIdx.x; t < ent.N * ent.Kpad; t += blockDim.x) {
        int nn = t / ent.Kpad;
        int k  = t - nn * ent.Kpad;
        float v = (k < ent.K) ? ldv(ent.src, (size_t)k * ent.N + nn, mode) : 0.0f;
        ent.dst[t] = f2bfb(v);
      }
      if (r == 0 && threadIdx.x == 0) flag[0] = mode;
    } else {
      for (int t2 = 0; t2 < 12; ++t2) {
        CvtEnt ent = ca.e[t2];
        for (int t = threadIdx.x; t < ent.n; t += blockDim.x)
          ent.dst[t] = ldv(ent.src, t, mode);
      }
    }
  }
}

// ---------------------------------------------------------------------------
// Grid KNN v8. v7 post-mortem: ~65% of issue work was the 350-instr bitonic
// flush, run 5-6x per wave (per-shell drains + pressure). v8 removes sorted
// top-16 maintenance entirely during the search:
//  * 128-entry LDS buffer per wave; INVARIANT: buffer holds every seen point
//    with key <= TH, where TH >= 16th-smallest key of seen (so it always
//    contains the true top-16 of the seen set).
//  * compact(): ballot-count binary search on f32 d2 bits (monotone) for a
//    TH with count in [16,TARGET] (wide band -> ~4-8 iters), then ballot/
//    mbcnt compaction. ~150 instrs vs 350. Dropped keys > TH >= current
//    16th >= final 16th -> exact. u64 low-word refine covers pathological
//    d2-bit ties (distinct indices guarantee termination).
//  * no per-shell drains: the stop test with a stale (larger) th is
//    conservative. First-tighten + cnt>=48 re-tighten bound the staleness.
//  * ONE final bitonic-64 sort -> lanes 0..15 = exact lax.top_k order.
// Same frozen d2, same u64 keys, same shell enumeration and stop bound as
// v7 -> nbr bit-identical.
// ---------------------------------------------------------------------------
#define GR 32
#define GR3 (GR*GR*GR)

__global__ __launch_bounds__(256) void hist_kernel(
    const float4* __restrict__ pos4, const u32* __restrict__ bbx,
    int* __restrict__ counts, int* __restrict__ cid, int n) {
  const int i = blockIdx.x * 256 + threadIdx.x;
  if (i >= n) return;
  const float mnx = bdec(bbx[0]), mny = bdec(bbx[1]), mnz = bdec(bbx[2]);
  const float ihx = (float)GR / fmaxf(bdec(bbx[3]) - mnx, 1e-20f);
  const float ihy = (float)GR / fmaxf(bdec(bbx[4]) - mny, 1e-20f);
  const float ihz = (float)GR / fmaxf(bdec(bbx[5]) - mnz, 1e-20f);
  float4 p = pos4[i];
  int cx = min(GR - 1, max(0, (int)((p.x - mnx) * ihx)));
  int cy = min(GR - 1, max(0, (int)((p.y - mny) * ihy)));
  int cz = min(GR - 1, max(0, (int)((p.z - mnz) * ihz)));
  int lin = (cz * GR + cy) * GR + cx;
  cid[i] = lin;
  atomicAdd(&counts[lin], 1);
}

__global__ __launch_bounds__(1024) void scan_kernel(
    const int* __restrict__ counts, int* __restrict__ cellstart,
    int* __restrict__ cursor) {
  __shared__ int part[1024];
  const int t = threadIdx.x;
  const int base = t * 32;
  int v[32];
  int s = 0;
#pragma unroll
  for (int k = 0; k < 32; ++k) { v[k] = counts[base + k]; s += v[k]; }
  part[t] = s;
  __syncthreads();
  for (int d = 1; d < 1024; d <<= 1) {
    int x = (t >= d) ? part[t - d] : 0;
    __syncthreads();
    part[t] += x;
    __syncthreads();
  }
  int off = part[t] - s;   // exclusive prefix of this 32-chunk
#pragma unroll
  for (int k = 0; k < 32; ++k) {
    cellstart[base + k] = off; cursor[base + k] = off; off += v[k];
  }
  if (t == 1023) { cellstart[GR3] = off; cursor[GR3] = off; }
}

__global__ __launch_bounds__(256) void scatter_kernel(
    const float4* __restrict__ pos4, const int* __restrict__ cid,
    int* __restrict__ cursor, int* __restrict__ sidx,
    float4* __restrict__ spos4, int n) {
  const int i = blockIdx.x * 256 + threadIdx.x;
  if (i >= n) return;
  int dst = atomicAdd(&cursor[cid[i]], 1);
  spos4[dst] = pos4[i];
  sidx[dst]  = i;
}

#define KNN8_WPB 8
#define KCAP 128

__global__ __launch_bounds__(512) void knn8_kernel(
    const float4* __restrict__ spos4,
    const int* __restrict__ sidx, const int* __restrict__ cellstart,
    const u32* __restrict__ bbx, int* __restrict__ nbr, int n) {
  __shared__ u64 buf[KNN8_WPB][KCAP];
  const int tid = threadIdx.x, lane = tid & 63, w = tid >> 6;
  const int g = blockIdx.x * KNN8_WPB + w;
  u64* wbuf = &buf[w][0];
  const float4 pi = spos4[g];       // targets in cell-sorted order
  const int target = sidx[g];

  const float mnx = bdec(bbx[0]), mny = bdec(bbx[1]), mnz = bdec(bbx[2]);
  const float ex = fmaxf(bdec(bbx[3]) - mnx, 1e-20f);
  const float ey = fmaxf(bdec(bbx[4]) - mny, 1e-20f);
  const float ez = fmaxf(bdec(bbx[5]) - mnz, 1e-20f);
  const float ihx = (float)GR / ex, ihy = (float)GR / ey, ihz = (float)GR / ez;
  const float hxf = ex * (1.0f / GR), hyf = ey * (1.0f / GR), hzf = ez * (1.0f / GR);
  const int cx = min(GR - 1, max(0, (int)((pi.x - mnx) * ihx)));
  const int cy = min(GR - 1, max(0, (int)((pi.y - mny) * ihy)));
  const int cz = min(GR - 1, max(0, (int)((pi.z - mnz) * ihz)));

  u64 TH = ~0ull;       // key upper bound defining the retained set
  float th = 3.4e38f;   // f32 filter: d2 <= th  <=>  d2bits <= (TH>>32)
  int cnt = 0;
  bool tight = false;
  int myseen = 0;       // per-lane partial; reduced at break checks

  // Tighten TH/th and compact retained set. Pre: cnt >= 16.
  // Post: retained = {key <= TH}, 16 <= cnt <= max(TARGET,64-band), th synced.
  auto compact = [&](int TARGET) {
    u64 k0 = wbuf[lane];
    u64 k1 = wbuf[64 + lane];
    const bool v0 = lane < cnt, v1 = (64 + lane) < cnt;
    const u32 d0 = (u32)(k0 >> 32), d1 = (u32)(k1 >> 32);
    u32 mn = min(v0 ? d0 : 0xffffffffu, v1 ? d1 : 0xffffffffu);
    u32 mx = max(v0 ? d0 : 0u, v1 ? d1 : 0u);
#pragma unroll
    for (int m = 32; m; m >>= 1) {
      mn = min(mn, (u32)__shfl_xor((int)mn, m, 64));
      mx = max(mx, (u32)__shfl_xor((int)mx, m, 64));
    }
    u32 lo32 = mn, hi32 = mx;   // count(d2bits <= mx) == cnt >= 16
    int cb = cnt;
    while (cb > TARGET && lo32 < hi32) {
      u32 mid = lo32 + ((hi32 - lo32) >> 1);
      int c = __popcll(__ballot(v0 && d0 <= mid)) +
              __popcll(__ballot(v1 && d1 <= mid));
      if (c >= 16) { hi32 = mid; cb = c; } else lo32 = mid + 1;
    }
    u64 THn = ((u64)hi32 << 32) | 0xffffffffull;
    if (cb > 64) {   // >48 ties at hi32: exact u64 refine (distinct idx)
      u64 l = (u64)hi32 << 32, h = THn;
      while (cb > 64 && l < h) {
        u64 mid = l + ((h - l) >> 1);
        int c = __popcll(__ballot(v0 && k0 <= mid)) +
                __popcll(__ballot(v1 && k1 <= mid));
        if (c >= 16) { h = mid; cb = c; } else l = mid + 1;
      }
      THn = h;
    }
    TH = THn;
    th = __uint_as_float((u32)(TH >> 32));   // finite (from data bits)
    bool kp0 = v0 && k0 <= TH, kp1 = v1 && k1 <= TH;
    u64 b0 = __ballot(kp0);
    u32 p0 = __builtin_amdgcn_mbcnt_lo((u32)b0, 0u);
    p0 = __builtin_amdgcn_mbcnt_hi((u32)(b0 >> 32), p0);
    u64 b1 = __ballot(kp1);
    u32 p1 = __builtin_amdgcn_mbcnt_lo((u32)b1, 0u);
    p1 = __builtin_amdgcn_mbcnt_hi((u32)(b1 >> 32), p1);
    int base1 = __popcll(b0);
    asm volatile("" ::: "memory");   // keep LDS reads above writes
    if (kp0) wbuf[p0] = k0;
    if (kp1) wbuf[base1 + p1] = k1;
    asm volatile("" ::: "memory");
    cnt = base1 + __popcll(b1);
    tight = true;
  };

  auto procSeg = [&](int p0, int p1) {
#pragma unroll 2
    for (int t0 = p0; t0 < p1; t0 += 64) {
      int gi = t0 + lane;
      bool in = gi < p1;
      float4 a = spos4[in ? gi : (p1 - 1)];
      float d2 = (pi.w + a.w) - 2.0f*(pi.x*a.x + pi.y*a.y + pi.z*a.z);  // frozen
      d2 = fmaxf(d2, 0.0f);
      bool pass = in && (d2 <= th);
      u64 bal = __ballot(pass);
      if (bal) {
        int pc = __popcll(bal);
        if (cnt + pc > KCAP) compact(32);   // post: cnt<=64 -> room for 64
        u32 mb = __builtin_amdgcn_mbcnt_lo((u32)bal, 0u);
        mb = __builtin_amdgcn_mbcnt_hi((u32)(bal >> 32), mb);
        if (pass)
          wbuf[cnt + mb] = ((u64)__float_as_uint(d2) << 32) | (u32)sidx[gi];
        cnt += pc;
      }
    }
  };

  // shell r=0: own cell (seeds th before shell-1)
  {
    const int oc = (cz * GR + cy) * GR + cx;
    const int oLo = cellstart[oc], oHi = cellstart[oc + 1];
    if (lane == 0) myseen += oHi - oLo;
    procSeg(oLo, oHi);
    if (cnt >= 16) compact(24);
  }

  for (int r = 1; r < GR; ++r) {
    const int x0 = max(cx - r, 0), x1 = min(cx + r, GR - 1);
    const int d1 = 2*r + 1, d2i = 2*r - 1;
    const int nA = 2 * d1;            // top/bottom slabs: 2 x (2r+1) rows
    const int nB = 2 * d2i;           // interior slabs, side rows
    const int nC = 2 * d2i * d2i;     // interior z,y: x-face cells
    const int S = nA + nB + nC;
    const u32 magic = 0xFFFFFFFFu / (u32)d2i + 1u;  // exact for our t range

    for (int b0i = 0; b0i < S; b0i += 64) {
      const int s = b0i + lane;
      int zc = 0, yc = 0, xa = 0, xb = -1;
      bool live = s < S;
      if (live) {
        if (s < nA) {
          int za = s >= d1;
          int dy = s - (za ? d1 : 0) - r;
          zc = cz + (za ? r : -r); yc = cy + dy; xa = x0; xb = x1;
        } else if (s < nA + nB) {
          int t = s - nA;
          int side = t >= d2i;
          int dz = t - (side ? d2i : 0) - (r - 1);
          zc = cz + dz; yc = cy + (side ? r : -r); xa = x0; xb = x1;
        } else {
          int t = s - nA - nB;
          int side = t & 1; t >>= 1;
          int dzi = (int)__umulhi((u32)t, magic);
          int dyi = t - dzi * d2i;
          zc = cz - r + 1 + dzi; yc = cy - r + 1 + dyi;
          int xcell = side ? cx + r : cx - r;
          xa = xcell; xb = xcell;
          live = ((unsigned)xcell < GR);
        }
        live = live && ((unsigned)zc < GR) && ((unsigned)yc < GR);
      }
      int lo = 0, hi = 0;
      if (live) {
        int base = (zc * GR + yc) * GR;
        lo = cellstart[base + xa];
        hi = cellstart[base + xb + 1];
        myseen += hi - lo;
      }
      u64 bal = __ballot(live && (hi > lo));
      while (bal) {
        int l = __builtin_ctzll(bal); bal &= bal - 1;
        int p0 = __shfl(lo, l, 64), p1 = __shfl(hi, l, 64);
        procSeg(p0, p1);
      }
    }
    // tighten before the stop test when first possible or notably stale
    if (cnt >= 16 && (!tight || cnt >= 48)) compact(24);

    // total seen (wave-uniform)
    int tot = myseen;
#pragma unroll
    for (int m = 32; m; m >>= 1) tot += __shfl_xor(tot, m, 64);
    if (tot >= n) break;                       // everything examined
    // unseen points lie outside box r; min distance to its interior faces
    float mind = 3.4e38f;
    if (cx - r > 0)      mind = fminf(mind, pi.x - (mnx + (float)(cx - r) * hxf));
    if (cx + r < GR - 1) mind = fminf(mind, (mnx + (float)(cx + r + 1) * hxf) - pi.x);
    if (cy - r > 0)      mind = fminf(mind, pi.y - (mny + (float)(cy - r) * hyf));
    if (cy + r < GR - 1) mind = fminf(mind, (mny + (float)(cy + r + 1) * hyf) - pi.y);
    if (cz - r > 0)      mind = fminf(mind, pi.z - (mnz + (float)(cz - r) * hzf));
    if (cz + r < GR - 1) mind = fminf(mind, (mnz + (float)(cz + r + 1) * hzf) - pi.z);
    float mind2 = mind * mind * 0.9999f - 1e-6f;   // margin >> fp rounding
    if (mind2 > th) break;
  }

  // final exact selection: retained set contains the true top-16
  if (cnt > 64) compact(32);
  u64 cand = (lane < cnt) ? wbuf[lane] : ~0ull;
  cand = sort64(cand, lane);
  if (lane < 16) nbr[(size_t)target * 16 + lane] = (int)(cand & 0xffffffffu);
}

// ---------------------------------------------------------------------------
// MFMA conv v6 (unchanged): REGISTER-LIVENESS restructure; GEMM1 one N-tile
// at a time; zero __syncthreads; numerics frozen.
// ---------------------------------------------------------------------------
template<int CIN, int CMID, int KT1, int NT, int KT2>
__global__ __launch_bounds__(256, 4) void conv_mfma6_kernel(
    const float* __restrict__ xf,             // [N,6] fp32 (CIN==6)
    const unsigned short* __restrict__ xb,    // [N,64] bf16 (CIN==64)
    const float4* __restrict__ pos4,
    const int* __restrict__ nbr,
    const int* __restrict__ flag,
    const unsigned short* __restrict__ WaT,   // [CMID][K1PAD] bf16
    const unsigned short* __restrict__ WbT,   // [CMID][CMID]  bf16
    const float* __restrict__ baf,
    const float* __restrict__ gmf,
    const float* __restrict__ btf,
    const float* __restrict__ bbf,
    unsigned short* __restrict__ xoutb,       // [N,CMID] bf16 ws (may be null)
    void* __restrict__ bout, size_t out_off)
{
  constexpr int K1PAD = KT1 * 32;
  constexpr int SB = CMID + 8;

  __shared__ unsigned short msgB[128 * SB];

  const int tid  = threadIdx.x;
  const int lane = tid & 63;
  const int w    = tid >> 6;
  const int quad = lane >> 4;
  const int cl   = lane & 15;
  const int node0 = blockIdx.x * 8;
  const int mode = flag[0];

  bf16x8 afr[2][KT1];
#pragma unroll
  for (int mt = 0; mt < 2; ++mt) {
    const int node = node0 + w*2 + mt;
    const int j = nbr[(size_t)node*16 + cl];
    const float4 pin = pos4[node];
    const float4 pj = pos4[j];
    const float rx = pj.x - pin.x, ry = pj.y - pin.y, rz = pj.z - pin.z;
    if constexpr (CIN == 64) {
#pragma unroll
      for (int kt = 0; kt < 2; ++kt)
        afr[mt][kt] = *(const bf16x8*)&xb[(size_t)j*64 + kt*32 + quad*8];
      unsigned short o[8] = {0,0,0,0,0,0,0,0};
      if (quad == 0) { o[0] = f2bfb(rx); o[1] = f2bfb(ry); o[2] = f2bfb(rz); }
      afr[mt][KT1-1] = *(bf16x8*)o;
    } else {  // CIN == 6
      unsigned short o[8] = {0,0,0,0,0,0,0,0};
      if (quad == 0) {
        const float* p = &xf[(size_t)j*6];
        o[0] = f2bfb(p[0]); o[1] = f2bfb(p[1]); o[2] = f2bfb(p[2]);
        o[3] = f2bfb(p[3]); o[4] = f2bfb(p[4]); o[5] = f2bfb(p[5]);
        o[6] = f2bfb(rx);   o[7] = f2bfb(ry);
      } else if (quad == 1) {
        o[0] = f2bfb(rz);
      }
      afr[mt][0] = *(bf16x8*)o;
    }
  }

  // ---- GEMM1 + bias + GN, ONE tile at a time (a1 live = 8 VGPR) ----
  const int grow = lane >> 1, ggl = lane & 1;    // GN thread mapping
#pragma unroll
  for (int nt = 0; nt < NT; ++nt) {
    f32x4 a1[2];
    a1[0] = (f32x4){0.f, 0.f, 0.f, 0.f};
    a1[1] = (f32x4){0.f, 0.f, 0.f, 0.f};
#pragma unroll
    for (int kt = 0; kt < KT1; ++kt) {
      bf16x8 bfr = *(const bf16x8*)&WaT[(size_t)(nt*16 + cl) * K1PAD + kt*32 + quad*8];
      a1[0] = __builtin_amdgcn_mfma_f32_16x16x32_bf16(afr[0][kt], bfr, a1[0], 0, 0, 0);
      a1[1] = __builtin_amdgcn_mfma_f32_16x16x32_bf16(afr[1][kt], bfr, a1[1], 0, 0, 0);
    }
    float bac = baf[nt*16 + cl];
#pragma unroll
    for (int mt = 0; mt < 2; ++mt)
#pragma unroll
      for (int reg = 0; reg < 4; ++reg)
        msgB[(w*32 + mt*16 + quad*4 + reg) * SB + nt*16 + cl] =
            f2bfb(a1[mt][reg] + bac);
    asm volatile("" ::: "memory");   // same-wave DS FIFO: write < read
    {
      const int cb = nt*16 + ggl*8;
      unsigned short* p = &msgB[(w*32 + grow) * SB + cb];
      u16x8 hv = *(const u16x8*)p;
      float vv[8];
#pragma unroll
      for (int e = 0; e < 8; ++e) vv[e] = bfb2f(hv[e]);
      float s = 0.f, q = 0.f;
#pragma unroll
      for (int e = 0; e < 8; ++e) { s += vv[e]; q += vv[e]*vv[e]; }
      float mu = s * 0.125f;
      float var = q * 0.125f - mu * mu;
      float inv = rsqrtf(fmaxf(var, 0.0f) + 1e-5f);
      unsigned short o[8];
#pragma unroll
      for (int e = 0; e < 8; ++e) {
        float t = (vv[e] - mu) * inv * gmf[cb+e] + btf[cb+e];
        o[e] = f2bfb(fmaxf(t, 0.0f));
      }
      *(bf16x8*)p = *(bf16x8*)o;
    }
    asm volatile("" ::: "memory");
  }

  // ---- GEMM2 (A from this wave's msgB band only) ----
  f32x4 acc2[2][NT];
#pragma unroll
  for (int mt = 0; mt < 2; ++mt)
#pragma unroll
    for (int nt = 0; nt < NT; ++nt) acc2[mt][nt] = (f32x4){0.f, 0.f, 0.f, 0.f};
#pragma unroll
  for (int kt = 0; kt < KT2; ++kt) {
    bf16x8 af0 = *(const bf16x8*)&msgB[(w*32 + cl)      * SB + kt*32 + quad*8];
    bf16x8 af1 = *(const bf16x8*)&msgB[(w*32 + 16 + cl) * SB + kt*32 + quad*8];
#pragma unroll
    for (int nt = 0; nt < NT; ++nt) {
      bf16x8 bfr = *(const bf16x8*)&WbT[(size_t)(nt*16 + cl) * CMID + kt*32 + quad*8];
      acc2[0][nt] = __builtin_amdgcn_mfma_f32_16x16x32_bf16(af0, bfr, acc2[0][nt], 0, 0, 0);
      acc2[1][nt] = __builtin_amdgcn_mfma_f32_16x16x32_bf16(af1, bfr, acc2[1][nt], 0, 0, 0);
    }
  }

#pragma unroll
  for (int mt = 0; mt < 2; ++mt) {
    int node = node0 + w*2 + mt;
#pragma unroll
    for (int nt = 0; nt < NT; ++nt) {
      float m = fmaxf(fmaxf(acc2[mt][nt][0], acc2[mt][nt][1]),
                      fmaxf(acc2[mt][nt][2], acc2[mt][nt][3]));
      m = fmaxf(m, __shfl_xor(m, 16, 64));
      m = fmaxf(m, __shfl_xor(m, 32, 64));
      float v = fmaxf(m + bbf[nt*16 + cl], 0.0f);
      if (quad == 0) {
        size_t oi = (size_t)node * CMID + nt*16 + cl;
        if (xoutb) xoutb[oi] = f2bfb(v);
        stv(bout, out_off + oi, mode, v);
      }
    }
  }
}

// ---------------------------------------------------------------------------
extern "C" void kernel_launch(void* const* d_in, const int* in_sizes, int n_in,
                              void* d_out, int out_size, void* d_ws, size_t ws_size,
                              hipStream_t stream) {
  (void)n_in; (void)ws_size; (void)in_sizes;
  int n = out_size / 256;
  if (n <= 0 || (n & 255)) n = 16384;

  float* ws = (float*)d_ws;
  int*    flag    = (int*)ws;                                       // 16 ints (0=mode, 4..9=bbox atomics)
  float4* pos4    = (float4*)(ws + 16);                             // 4n
  float*  h0      = ws + 16 + (size_t)4*n;                          // 6n
  int*    nbr     = (int*)(ws + 16 + (size_t)10*n);                 // 16n
  unsigned short* h1b = (unsigned short*)(ws + 16 + (size_t)26*n);  // 32n
  unsigned short* h2b = (unsigned short*)(ws + 16 + (size_t)58*n);  // 32n
  float*  vbuf    = ws + 16 + (size_t)90*n;                         // 1024
  unsigned short* wtbuf = (unsigned short*)(vbuf + 1024);           // 45056 shorts

  // grid-knn buffers (after wtbuf = 22528 floats)
  float* gbase = vbuf + 1024 + 22528;
  int*    cid       = (int*)gbase;            // n
  int*    counts    = cid + n;                // 32768
  int*    cellstart = counts + GR3;           // 32769 (padded to 32772)
  int*    cursor    = cellstart + 32772;      // 32769 (padded to 32772)
  int*    sidx      = cursor + 32772;         // n
  float4* spos4     = (float4*)(sidx + n);    // 4n floats (16B aligned)

  const int vsz[12] = {64,64,64,64, 64,64,64,64, 128,128,128,128};
  const int vsrc[12] = {3,4,5,7, 9,10,11,13, 15,16,17,19};
  CvtArgs ca;
  float* vptr[12];
  {
    int off = 0;
    for (int t = 0; t < 12; ++t) {
      ca.e[t].src = d_in[vsrc[t]];
      ca.e[t].dst = vbuf + off;
      ca.e[t].n   = vsz[t];
      vptr[t] = vbuf + off;
      off += vsz[t];
    }
  }
  const int wK[6]    = {9, 64, 67, 64, 67, 128};
  const int wN[6]    = {64, 64, 64, 64, 128, 128};
  const int wKp[6]   = {32, 64, 96, 64, 96, 128};
  const int wsrc[6]  = {2, 6, 8, 12, 14, 18};
  WArgs wa;
  unsigned short* wptr[6];
  {
    int off = 0;
    for (int t = 0; t < 6; ++t) {
      wa.e[t].src  = d_in[wsrc[t]];
      wa.e[t].dst  = wtbuf + off;
      wa.e[t].K    = wK[t];
      wa.e[t].N    = wN[t];
      wa.e[t].Kpad = wKp[t];
      wptr[t] = wtbuf + off;
      off += wN[t] * wKp[t];
    }
  }

  // init bbox atomics + counts (stream-ordered, graph-capture legal)
  u32* bbx = (u32*)ws + 4;
  hipMemsetAsync(bbx,     0xFF, 12, stream);          // min slots
  hipMemsetAsync(bbx + 3, 0x00, 12, stream);          // max slots
  hipMemsetAsync(counts,  0x00, GR3 * sizeof(int), stream);

  setup_kernel<<<n/256 + 7, 256, 0, stream>>>(
      d_in[0], d_in[1], wa, ca, flag, pos4, h0, n);

  hist_kernel<<<n/256, 256, 0, stream>>>(pos4, bbx, counts, cid, n);
  scan_kernel<<<1, 1024, 0, stream>>>(counts, cellstart, cursor);
  scatter_kernel<<<n/256, 256, 0, stream>>>(pos4, cid, cursor, sidx, spos4, n);
  knn8_kernel<<<n/KNN8_WPB, 512, 0, stream>>>(spos4, sidx, cellstart,
                                              bbx, nbr, n);

  // <CIN, CMID, KT1, NT, KT2>
  conv_mfma6_kernel<6, 64, 1, 4, 2><<<n/8, 256, 0, stream>>>(
      h0, (const unsigned short*)nullptr, pos4, nbr, flag, wptr[0], wptr[1],
      vptr[0], vptr[1], vptr[2], vptr[3], h1b, d_out, (size_t)0);
  conv_mfma6_kernel<64, 64, 3, 4, 2><<<n/8, 256, 0, stream>>>(
      (const float*)nullptr, h1b, pos4, nbr, flag, wptr[2], wptr[3],
      vptr[4], vptr[5], vptr[6], vptr[7], h2b, d_out, (size_t)n*64);
  conv_mfma6_kernel<64, 128, 3, 8, 4><<<n/8, 256, 0, stream>>>(
      (const float*)nullptr, h2b, pos4, nbr, flag, wptr[4], wptr[5],
      vptr[8], vptr[9], vptr[10], vptr[11],
      (unsigned short*)nullptr, d_out, (size_t)n*128);
}

// Round 5
// 351.620 us; speedup vs baseline: 1.1111x; 1.1111x over previous
//
#include <hip/hip_runtime.h>
#include <hip/hip_bf16.h>
#include <stdint.h>

typedef unsigned long long u64;
typedef unsigned int u32;
typedef __attribute__((ext_vector_type(8))) short bf16x8;
typedef __attribute__((ext_vector_type(8))) unsigned short u16x8;
typedef __attribute__((ext_vector_type(4))) float f32x4;

__device__ __forceinline__ float ldv(const void* p, size_t idx, int mode) {
  return mode ? __bfloat162float(((const __hip_bfloat16*)p)[idx])
              : ((const float*)p)[idx];
}
__device__ __forceinline__ void stv(void* p, size_t idx, int mode, float v) {
  if (mode) ((__hip_bfloat16*)p)[idx] = __float2bfloat16(v);
  else      ((float*)p)[idx] = v;
}
__device__ __forceinline__ unsigned short f2bfb(float f) {  // RNE f32->bf16 bits
  u32 u = __float_as_uint(f);
  u32 r = u + 0x7fffu + ((u >> 16) & 1u);
  return (unsigned short)(r >> 16);
}
__device__ __forceinline__ float bfb2f(unsigned short b) {
  return __uint_as_float((u32)b << 16);
}
__device__ __forceinline__ u64 shfl64(u64 v, int src) {
  int lo = __shfl((int)(u32)(v & 0xffffffffu), src, 64);
  int hi = __shfl((int)(u32)(v >> 32), src, 64);
  return ((u64)(u32)hi << 32) | (u32)lo;
}
__device__ __forceinline__ u64 shflxor64(u64 v, int m) {
  int lo = __shfl_xor((int)(u32)(v & 0xffffffffu), m, 64);
  int hi = __shfl_xor((int)(u32)(v >> 32), m, 64);
  return ((u64)(u32)hi << 32) | (u32)lo;
}
__device__ __forceinline__ u64 shfl64w16(u64 v, int src) {  // width-16 shfl
  int lo = __shfl((int)(u32)(v & 0xffffffffu), src, 16);
  int hi = __shfl((int)(u32)(v >> 32), src, 16);
  return ((u64)(u32)hi << 32) | (u32)lo;
}

// monotonic float<->uint encoding for atomicMin/Max-based bbox
__device__ __forceinline__ u32 benc(float f) {
  u32 u = __float_as_uint(f);
  return (u & 0x80000000u) ? ~u : (u | 0x80000000u);
}
__device__ __forceinline__ float bdec(u32 k) {
  return (k & 0x80000000u) ? __uint_as_float(k ^ 0x80000000u)
                           : __uint_as_float(~k);
}

__global__ void PointNetSimple_61409442398998_kernel() {}

// ---------------------------------------------------------------------------
// setup: dtype-detect + weight transpose/convert + vector cvt + prep.
// Prep branch also contributes bbox atomics (bbx pre-init'd by hipMemsetAsync).
// ---------------------------------------------------------------------------
struct CvtEnt { const void* src; float* dst; int n; };
struct CvtArgs { CvtEnt e[12]; };
struct WEnt { const void* src; unsigned short* dst; int K, N, Kpad; };
struct WArgs { WEnt e[6]; };

__global__ void setup_kernel(const void* __restrict__ pos,
                             const void* __restrict__ nrm,
                             WArgs wa, CvtArgs ca,
                             int* __restrict__ flag,
                             float4* __restrict__ pos4,
                             float* __restrict__ h0, int n) {
  const unsigned short* u16p = (const unsigned short*)pos;
  int cnt = 0;
  for (int k = 0; k < 32; ++k) {
    int e = (u16p[k] >> 7) & 0xff;
    if (e >= 110 && e <= 140) cnt++;
  }
  const int mode = (cnt >= 26) ? 1 : 0;

  const int nprep = n >> 8;
  const int b = blockIdx.x;
  if (b < nprep) {
    int i = b * 256 + threadIdx.x;
    float x = ldv(pos, 3*(size_t)i+0, mode);
    float y = ldv(pos, 3*(size_t)i+1, mode);
    float z = ldv(pos, 3*(size_t)i+2, mode);
    pos4[i] = make_float4(x, y, z, x*x + y*y + z*z);
    h0[6*(size_t)i+0] = x; h0[6*(size_t)i+1] = y; h0[6*(size_t)i+2] = z;
    h0[6*(size_t)i+3] = ldv(nrm, 3*(size_t)i+0, mode);
    h0[6*(size_t)i+4] = ldv(nrm, 3*(size_t)i+1, mode);
    h0[6*(size_t)i+5] = ldv(nrm, 3*(size_t)i+2, mode);
    // bbox contribution (bbx = ((u32*)flag)+4..9, init'd by memset)
    float bmn[3] = {x, y, z}, bmx[3] = {x, y, z};
#pragma unroll
    for (int m = 32; m; m >>= 1) {
#pragma unroll
      for (int k = 0; k < 3; ++k) {
        bmn[k] = fminf(bmn[k], __shfl_xor(bmn[k], m, 64));
        bmx[k] = fmaxf(bmx[k], __shfl_xor(bmx[k], m, 64));
      }
    }
    if ((threadIdx.x & 63) == 0) {
      u32* bb = (u32*)flag;
#pragma unroll
      for (int k = 0; k < 3; ++k) {
        atomicMin(&bb[4 + k], benc(bmn[k]));
        atomicMax(&bb[7 + k], benc(bmx[k]));
      }
    }
  } else {
    int r = b - nprep;
    if (r < 6) {
      WEnt ent = wa.e[r];
      for (int t = threadIdx.x; t < ent.N * ent.Kpad; t += blockDim.x) {
        int nn = t / ent.Kpad;
        int k  = t - nn * ent.Kpad;
        float v = (k < ent.K) ? ldv(ent.src, (size_t)k * ent.N + nn, mode) : 0.0f;
        ent.dst[t] = f2bfb(v);
      }
      if (r == 0 && threadIdx.x == 0) flag[0] = mode;
    } else {
      for (int t2 = 0; t2 < 12; ++t2) {
        CvtEnt ent = ca.e[t2];
        for (int t = threadIdx.x; t < ent.n; t += blockDim.x)
          ent.dst[t] = ldv(ent.src, t, mode);
      }
    }
  }
}

// ---------------------------------------------------------------------------
// knn flush (proven exact merge): bitonic sort of pending candidates,
// reverse-merge with current top-16, clean-16. u64 keys = exact lax.top_k
// order (d2 bits << 32 | original index). NaN-guard: sentinel -> +inf th.
// CAP=64 is bit-identical to the proven path. CAP=32 (valid when cnt<=32).
// ---------------------------------------------------------------------------
template<int CAP>
__device__ __forceinline__ void knn_flush(u64* __restrict__ wbuf, int& cnt,
                                          u64& val, u64& t15, float& th,
                                          int lane) {
  u64 cand = (lane < cnt) ? wbuf[lane] : ~0ull;
#pragma unroll
  for (int k = 2; k <= CAP; k <<= 1) {
#pragma unroll
    for (int j = k >> 1; j > 0; j >>= 1) {
      u64 other = shflxor64(cand, j);
      bool up    = ((lane & k) == 0) || (k == CAP);
      bool lower = ((lane & j) == 0);
      bool keepMin = (up == lower);
      u64 mn = cand < other ? cand : other;
      u64 mx = cand < other ? other : cand;
      cand = keepMin ? mn : mx;
    }
  }
  u64 rev = shfl64w16(cand, 15 - (lane & 15));
  u64 lo = val < rev ? val : rev;
#pragma unroll
  for (int j = 8; j > 0; j >>= 1) {
    u64 other = shflxor64(lo, j);
    bool lower = ((lane & j) == 0);
    u64 mn = lo < other ? lo : other;
    u64 mx = lo < other ? other : lo;
    lo = lower ? mn : mx;
  }
  val = (lane < 16) ? lo : ~0ull;
  t15 = shfl64(val, 15);
  u32 thb = (u32)(t15 >> 32);
  th = (thb == 0xffffffffu) ? 3.4e38f : __uint_as_float(thb);
  cnt = 0;
}

// ---------------------------------------------------------------------------
// Grid KNN v7 (restored from the proven 105us round-3 version; knn8's
// threshold-compact variant regressed to 136us -> reverted). One tweak:
// stale-th stop screening — test the stop bound with the current (possibly
// stale, >= true) th BEFORE flushing; flush only if the stale test fails.
// th_stale >= th_true makes the stale stop conservative; pending candidates
// are merged by the final flush before the nbr write. -> bit-identical nbr.
// ---------------------------------------------------------------------------
#define GR 32
#define GR3 (GR*GR*GR)

__global__ __launch_bounds__(256) void hist_kernel(
    const float4* __restrict__ pos4, const u32* __restrict__ bbx,
    int* __restrict__ counts, int* __restrict__ cid, int n) {
  const int i = blockIdx.x * 256 + threadIdx.x;
  if (i >= n) return;
  const float mnx = bdec(bbx[0]), mny = bdec(bbx[1]), mnz = bdec(bbx[2]);
  const float ihx = (float)GR / fmaxf(bdec(bbx[3]) - mnx, 1e-20f);
  const float ihy = (float)GR / fmaxf(bdec(bbx[4]) - mny, 1e-20f);
  const float ihz = (float)GR / fmaxf(bdec(bbx[5]) - mnz, 1e-20f);
  float4 p = pos4[i];
  int cx = min(GR - 1, max(0, (int)((p.x - mnx) * ihx)));
  int cy = min(GR - 1, max(0, (int)((p.y - mny) * ihy)));
  int cz = min(GR - 1, max(0, (int)((p.z - mnz) * ihz)));
  int lin = (cz * GR + cy) * GR + cx;
  cid[i] = lin;
  atomicAdd(&counts[lin], 1);
}

__global__ __launch_bounds__(1024) void scan_kernel(
    const int* __restrict__ counts, int* __restrict__ cellstart,
    int* __restrict__ cursor) {
  __shared__ int part[1024];
  const int t = threadIdx.x;
  const int base = t * 32;
  int v[32];
  int s = 0;
#pragma unroll
  for (int k = 0; k < 32; ++k) { v[k] = counts[base + k]; s += v[k]; }
  part[t] = s;
  __syncthreads();
  for (int d = 1; d < 1024; d <<= 1) {
    int x = (t >= d) ? part[t - d] : 0;
    __syncthreads();
    part[t] += x;
    __syncthreads();
  }
  int off = part[t] - s;   // exclusive prefix of this 32-chunk
#pragma unroll
  for (int k = 0; k < 32; ++k) {
    cellstart[base + k] = off; cursor[base + k] = off; off += v[k];
  }
  if (t == 1023) { cellstart[GR3] = off; cursor[GR3] = off; }
}

__global__ __launch_bounds__(256) void scatter_kernel(
    const float4* __restrict__ pos4, const int* __restrict__ cid,
    int* __restrict__ cursor, int* __restrict__ sidx,
    float4* __restrict__ spos4, int n) {
  const int i = blockIdx.x * 256 + threadIdx.x;
  if (i >= n) return;
  int dst = atomicAdd(&cursor[cid[i]], 1);
  spos4[dst] = pos4[i];
  sidx[dst]  = i;
}

#define KNN7_WPB 4
__global__ __launch_bounds__(256) void knn7_kernel(
    const float4* __restrict__ spos4,
    const int* __restrict__ sidx, const int* __restrict__ cellstart,
    const u32* __restrict__ bbx, int* __restrict__ nbr, int n) {
  __shared__ u64 buf[KNN7_WPB][72];
  const int tid = threadIdx.x, lane = tid & 63, w = tid >> 6;
  const int g = blockIdx.x * KNN7_WPB + w;
  u64* wbuf = &buf[w][0];
  const float4 pi = spos4[g];       // targets in cell-sorted order
  const int target = sidx[g];

  const float mnx = bdec(bbx[0]), mny = bdec(bbx[1]), mnz = bdec(bbx[2]);
  const float ex = fmaxf(bdec(bbx[3]) - mnx, 1e-20f);
  const float ey = fmaxf(bdec(bbx[4]) - mny, 1e-20f);
  const float ez = fmaxf(bdec(bbx[5]) - mnz, 1e-20f);
  const float ihx = (float)GR / ex, ihy = (float)GR / ey, ihz = (float)GR / ez;
  const float hxf = ex * (1.0f / GR), hyf = ey * (1.0f / GR), hzf = ez * (1.0f / GR);
  const int cx = min(GR - 1, max(0, (int)((pi.x - mnx) * ihx)));
  const int cy = min(GR - 1, max(0, (int)((pi.y - mny) * ihy)));
  const int cz = min(GR - 1, max(0, (int)((pi.z - mnz) * ihz)));

  u64 val = ~0ull, t15 = ~0ull;
  float th = 3.4e38f;
  int cnt = 0;
  int myseen = 0;   // per-lane partial; reduced at break checks

  auto doFlush = [&]() {
    if (cnt <= 32) knn_flush<32>(wbuf, cnt, val, t15, th, lane);
    else           knn_flush<64>(wbuf, cnt, val, t15, th, lane);
  };

  auto procSeg = [&](int p0, int p1) {
#pragma unroll 2
    for (int t0 = p0; t0 < p1; t0 += 64) {
      int gi = t0 + lane;
      bool in = gi < p1;
      float4 a = spos4[in ? gi : (p1 - 1)];
      float d2 = (pi.w + a.w) - 2.0f*(pi.x*a.x + pi.y*a.y + pi.z*a.z);  // frozen
      d2 = fmaxf(d2, 0.0f);
      bool pass = in && (d2 <= th);
      u64 bal = __ballot(pass);
      if (bal) {
        int pc = __popcll(bal);
        if (cnt + pc > 64) doFlush();
        u32 mb = __builtin_amdgcn_mbcnt_lo((u32)bal, 0u);
        mb = __builtin_amdgcn_mbcnt_hi((u32)(bal >> 32), mb);
        if (pass)
          wbuf[cnt + mb] = ((u64)__float_as_uint(d2) << 32) | (u32)sidx[gi];
        cnt += pc;
      }
    }
  };

  // shell r=0: own cell (seeds th before shell-1)
  {
    const int oc = (cz * GR + cy) * GR + cx;
    const int oLo = cellstart[oc], oHi = cellstart[oc + 1];
    if (lane == 0) myseen += oHi - oLo;
    procSeg(oLo, oHi);
    if (cnt > 0) doFlush();
  }

  for (int r = 1; r < GR; ++r) {
    const int x0 = max(cx - r, 0), x1 = min(cx + r, GR - 1);
    const int d1 = 2*r + 1, d2i = 2*r - 1;
    const int nA = 2 * d1;            // top/bottom slabs: 2 x (2r+1) rows
    const int nB = 2 * d2i;           // interior slabs, side rows
    const int nC = 2 * d2i * d2i;     // interior z,y: x-face cells
    const int S = nA + nB + nC;
    const u32 magic = 0xFFFFFFFFu / (u32)d2i + 1u;  // exact for our t range

    for (int b0 = 0; b0 < S; b0 += 64) {
      const int s = b0 + lane;
      int zc = 0, yc = 0, xa = 0, xb = -1;
      bool live = s < S;
      if (live) {
        if (s < nA) {
          int za = s >= d1;
          int dy = s - (za ? d1 : 0) - r;
          zc = cz + (za ? r : -r); yc = cy + dy; xa = x0; xb = x1;
        } else if (s < nA + nB) {
          int t = s - nA;
          int side = t >= d2i;
          int dz = t - (side ? d2i : 0) - (r - 1);
          zc = cz + dz; yc = cy + (side ? r : -r); xa = x0; xb = x1;
        } else {
          int t = s - nA - nB;
          int side = t & 1; t >>= 1;
          int dzi = (int)__umulhi((u32)t, magic);
          int dyi = t - dzi * d2i;
          zc = cz - r + 1 + dzi; yc = cy - r + 1 + dyi;
          int xcell = side ? cx + r : cx - r;
          xa = xcell; xb = xcell;
          live = ((unsigned)xcell < GR);
        }
        live = live && ((unsigned)zc < GR) && ((unsigned)yc < GR);
      }
      int lo = 0, hi = 0;
      if (live) {
        int base = (zc * GR + yc) * GR;
        lo = cellstart[base + xa];
        hi = cellstart[base + xb + 1];
        myseen += hi - lo;
      }
      u64 bal = __ballot(live && (hi > lo));
      while (bal) {
        int l = __builtin_ctzll(bal); bal &= bal - 1;
        int p0 = __shfl(lo, l, 64), p1 = __shfl(hi, l, 64);
        procSeg(p0, p1);
      }
    }

    // total seen (wave-uniform)
    int tot = myseen;
#pragma unroll
    for (int m = 32; m; m >>= 1) tot += __shfl_xor(tot, m, 64);
    if (tot >= n) break;        // everything examined (pending merged below)
    // unseen points lie outside box r; min distance to its interior faces
    float mind = 3.4e38f;
    if (cx - r > 0)      mind = fminf(mind, pi.x - (mnx + (float)(cx - r) * hxf));
    if (cx + r < GR - 1) mind = fminf(mind, (mnx + (float)(cx + r + 1) * hxf) - pi.x);
    if (cy - r > 0)      mind = fminf(mind, pi.y - (mny + (float)(cy - r) * hyf));
    if (cy + r < GR - 1) mind = fminf(mind, (mny + (float)(cy + r + 1) * hyf) - pi.y);
    if (cz - r > 0)      mind = fminf(mind, pi.z - (mnz + (float)(cz - r) * hzf));
    if (cz + r < GR - 1) mind = fminf(mind, (mnz + (float)(cz + r + 1) * hzf) - pi.z);
    float mind2 = mind * mind * 0.9999f - 1e-6f;   // margin >> fp rounding
    if (mind2 > th) break;      // stale-th screen (th >= true 16th: valid)
    if (cnt > 0) {
      doFlush();                // tighten th, then retest
      if (mind2 > th) break;
    }
  }
  if (cnt > 0) doFlush();
  if (lane < 16) nbr[(size_t)target * 16 + lane] = (int)(val & 0xffffffffu);
}

// ---------------------------------------------------------------------------
// MFMA conv v7: latency-oriented restructure of v6 (numerics bit-identical —
// same ops, same per-(mt,nt) kt-ascending accumulation, same epilogue math).
//  * GEMM1: weight fragments for nt+1 prefetched before nt's MFMA block;
//    the ~200cy L2 latency hides under nt's GN work.
//  * GEMM2: nt-outer/kt-inner; A-fragments ds_read ONCE into registers;
//    per-nt weight prefetch one tile ahead; per-nt epilogue fused in
//    (acc2 shrinks 2xNTx4 -> 2x4 VGPR; stores overlap compute).
// ---------------------------------------------------------------------------
template<int CIN, int CMID, int KT1, int NT, int KT2>
__global__ __launch_bounds__(256, 4) void conv_mfma7_kernel(
    const float* __restrict__ xf,             // [N,6] fp32 (CIN==6)
    const unsigned short* __restrict__ xb,    // [N,64] bf16 (CIN==64)
    const float4* __restrict__ pos4,
    const int* __restrict__ nbr,
    const int* __restrict__ flag,
    const unsigned short* __restrict__ WaT,   // [CMID][K1PAD] bf16
    const unsigned short* __restrict__ WbT,   // [CMID][CMID]  bf16
    const float* __restrict__ baf,
    const float* __restrict__ gmf,
    const float* __restrict__ btf,
    const float* __restrict__ bbf,
    unsigned short* __restrict__ xoutb,       // [N,CMID] bf16 ws (may be null)
    void* __restrict__ bout, size_t out_off)
{
  constexpr int K1PAD = KT1 * 32;
  constexpr int SB = CMID + 8;

  __shared__ unsigned short msgB[128 * SB];

  const int tid  = threadIdx.x;
  const int lane = tid & 63;
  const int w    = tid >> 6;
  const int quad = lane >> 4;
  const int cl   = lane & 15;
  const int node0 = blockIdx.x * 8;
  const int mode = flag[0];

  bf16x8 afr[2][KT1];
#pragma unroll
  for (int mt = 0; mt < 2; ++mt) {
    const int node = node0 + w*2 + mt;
    const int j = nbr[(size_t)node*16 + cl];
    const float4 pin = pos4[node];
    const float4 pj = pos4[j];
    const float rx = pj.x - pin.x, ry = pj.y - pin.y, rz = pj.z - pin.z;
    if constexpr (CIN == 64) {
#pragma unroll
      for (int kt = 0; kt < 2; ++kt)
        afr[mt][kt] = *(const bf16x8*)&xb[(size_t)j*64 + kt*32 + quad*8];
      unsigned short o[8] = {0,0,0,0,0,0,0,0};
      if (quad == 0) { o[0] = f2bfb(rx); o[1] = f2bfb(ry); o[2] = f2bfb(rz); }
      afr[mt][KT1-1] = *(bf16x8*)o;
    } else {  // CIN == 6
      unsigned short o[8] = {0,0,0,0,0,0,0,0};
      if (quad == 0) {
        const float* p = &xf[(size_t)j*6];
        o[0] = f2bfb(p[0]); o[1] = f2bfb(p[1]); o[2] = f2bfb(p[2]);
        o[3] = f2bfb(p[3]); o[4] = f2bfb(p[4]); o[5] = f2bfb(p[5]);
        o[6] = f2bfb(rx);   o[7] = f2bfb(ry);
      } else if (quad == 1) {
        o[0] = f2bfb(rz);
      }
      afr[mt][0] = *(bf16x8*)o;
    }
  }

  // ---- GEMM1 + bias + GN, one N-tile at a time; weights prefetched ----
  const int grow = lane >> 1, ggl = lane & 1;    // GN thread mapping
  bf16x8 w1c[KT1], w1n[KT1];
#pragma unroll
  for (int kt = 0; kt < KT1; ++kt)
    w1c[kt] = *(const bf16x8*)&WaT[(size_t)cl * K1PAD + kt*32 + quad*8];
#pragma unroll
  for (int nt = 0; nt < NT; ++nt) {
    if (nt + 1 < NT) {
#pragma unroll
      for (int kt = 0; kt < KT1; ++kt)
        w1n[kt] = *(const bf16x8*)&WaT[(size_t)((nt+1)*16 + cl) * K1PAD + kt*32 + quad*8];
    }
    f32x4 a1[2];
    a1[0] = (f32x4){0.f, 0.f, 0.f, 0.f};
    a1[1] = (f32x4){0.f, 0.f, 0.f, 0.f};
#pragma unroll
    for (int kt = 0; kt < KT1; ++kt) {
      a1[0] = __builtin_amdgcn_mfma_f32_16x16x32_bf16(afr[0][kt], w1c[kt], a1[0], 0, 0, 0);
      a1[1] = __builtin_amdgcn_mfma_f32_16x16x32_bf16(afr[1][kt], w1c[kt], a1[1], 0, 0, 0);
    }
    float bac = baf[nt*16 + cl];
#pragma unroll
    for (int mt = 0; mt < 2; ++mt)
#pragma unroll
      for (int reg = 0; reg < 4; ++reg)
        msgB[(w*32 + mt*16 + quad*4 + reg) * SB + nt*16 + cl] =
            f2bfb(a1[mt][reg] + bac);
    asm volatile("" ::: "memory");   // same-wave DS FIFO: write < read
    {
      const int cb = nt*16 + ggl*8;
      unsigned short* p = &msgB[(w*32 + grow) * SB + cb];
      u16x8 hv = *(const u16x8*)p;
      float vv[8];
#pragma unroll
      for (int e = 0; e < 8; ++e) vv[e] = bfb2f(hv[e]);
      float s = 0.f, q = 0.f;
#pragma unroll
      for (int e = 0; e < 8; ++e) { s += vv[e]; q += vv[e]*vv[e]; }
      float mu = s * 0.125f;
      float var = q * 0.125f - mu * mu;
      float inv = rsqrtf(fmaxf(var, 0.0f) + 1e-5f);
      unsigned short o[8];
#pragma unroll
      for (int e = 0; e < 8; ++e) {
        float t = (vv[e] - mu) * inv * gmf[cb+e] + btf[cb+e];
        o[e] = f2bfb(fmaxf(t, 0.0f));
      }
      *(bf16x8*)p = *(bf16x8*)o;
    }
    asm volatile("" ::: "memory");
#pragma unroll
    for (int kt = 0; kt < KT1; ++kt) w1c[kt] = w1n[kt];
  }

  // ---- GEMM2: A-fragments to registers once; nt-outer with fused epilogue
  bf16x8 af0[KT2], af1[KT2];
#pragma unroll
  for (int kt = 0; kt < KT2; ++kt) {
    af0[kt] = *(const bf16x8*)&msgB[(w*32 + cl)      * SB + kt*32 + quad*8];
    af1[kt] = *(const bf16x8*)&msgB[(w*32 + 16 + cl) * SB + kt*32 + quad*8];
  }
  bf16x8 w2c[KT2], w2n[KT2];
#pragma unroll
  for (int kt = 0; kt < KT2; ++kt)
    w2c[kt] = *(const bf16x8*)&WbT[(size_t)cl * CMID + kt*32 + quad*8];
#pragma unroll
  for (int nt = 0; nt < NT; ++nt) {
    if (nt + 1 < NT) {
#pragma unroll
      for (int kt = 0; kt < KT2; ++kt)
        w2n[kt] = *(const bf16x8*)&WbT[(size_t)((nt+1)*16 + cl) * CMID + kt*32 + quad*8];
    }
    f32x4 a2[2];
    a2[0] = (f32x4){0.f, 0.f, 0.f, 0.f};
    a2[1] = (f32x4){0.f, 0.f, 0.f, 0.f};
#pragma unroll
    for (int kt = 0; kt < KT2; ++kt) {
      a2[0] = __builtin_amdgcn_mfma_f32_16x16x32_bf16(af0[kt], w2c[kt], a2[0], 0, 0, 0);
      a2[1] = __builtin_amdgcn_mfma_f32_16x16x32_bf16(af1[kt], w2c[kt], a2[1], 0, 0, 0);
    }
#pragma unroll
    for (int mt = 0; mt < 2; ++mt) {
      int node = node0 + w*2 + mt;
      float m = fmaxf(fmaxf(a2[mt][0], a2[mt][1]),
                      fmaxf(a2[mt][2], a2[mt][3]));
      m = fmaxf(m, __shfl_xor(m, 16, 64));
      m = fmaxf(m, __shfl_xor(m, 32, 64));
      float v = fmaxf(m + bbf[nt*16 + cl], 0.0f);
      if (quad == 0) {
        size_t oi = (size_t)node * CMID + nt*16 + cl;
        if (xoutb) xoutb[oi] = f2bfb(v);
        stv(bout, out_off + oi, mode, v);
      }
    }
#pragma unroll
    for (int kt = 0; kt < KT2; ++kt) w2c[kt] = w2n[kt];
  }
}

// ---------------------------------------------------------------------------
extern "C" void kernel_launch(void* const* d_in, const int* in_sizes, int n_in,
                              void* d_out, int out_size, void* d_ws, size_t ws_size,
                              hipStream_t stream) {
  (void)n_in; (void)ws_size; (void)in_sizes;
  int n = out_size / 256;
  if (n <= 0 || (n & 255)) n = 16384;

  float* ws = (float*)d_ws;
  int*    flag    = (int*)ws;                                       // 16 ints (0=mode, 4..9=bbox atomics)
  float4* pos4    = (float4*)(ws + 16);                             // 4n
  float*  h0      = ws + 16 + (size_t)4*n;                          // 6n
  int*    nbr     = (int*)(ws + 16 + (size_t)10*n);                 // 16n
  unsigned short* h1b = (unsigned short*)(ws + 16 + (size_t)26*n);  // 32n
  unsigned short* h2b = (unsigned short*)(ws + 16 + (size_t)58*n);  // 32n
  float*  vbuf    = ws + 16 + (size_t)90*n;                         // 1024
  unsigned short* wtbuf = (unsigned short*)(vbuf + 1024);           // 45056 shorts

  // grid-knn buffers (after wtbuf = 22528 floats)
  float* gbase = vbuf + 1024 + 22528;
  int*    cid       = (int*)gbase;            // n
  int*    counts    = cid + n;                // 32768
  int*    cellstart = counts + GR3;           // 32769 (padded to 32772)
  int*    cursor    = cellstart + 32772;      // 32769 (padded to 32772)
  int*    sidx      = cursor + 32772;         // n
  float4* spos4     = (float4*)(sidx + n);    // 4n floats (16B aligned)

  const int vsz[12] = {64,64,64,64, 64,64,64,64, 128,128,128,128};
  const int vsrc[12] = {3,4,5,7, 9,10,11,13, 15,16,17,19};
  CvtArgs ca;
  float* vptr[12];
  {
    int off = 0;
    for (int t = 0; t < 12; ++t) {
      ca.e[t].src = d_in[vsrc[t]];
      ca.e[t].dst = vbuf + off;
      ca.e[t].n   = vsz[t];
      vptr[t] = vbuf + off;
      off += vsz[t];
    }
  }
  const int wK[6]    = {9, 64, 67, 64, 67, 128};
  const int wN[6]    = {64, 64, 64, 64, 128, 128};
  const int wKp[6]   = {32, 64, 96, 64, 96, 128};
  const int wsrc[6]  = {2, 6, 8, 12, 14, 18};
  WArgs wa;
  unsigned short* wptr[6];
  {
    int off = 0;
    for (int t = 0; t < 6; ++t) {
      wa.e[t].src  = d_in[wsrc[t]];
      wa.e[t].dst  = wtbuf + off;
      wa.e[t].K    = wK[t];
      wa.e[t].N    = wN[t];
      wa.e[t].Kpad = wKp[t];
      wptr[t] = wtbuf + off;
      off += wN[t] * wKp[t];
    }
  }

  // init bbox atomics + counts (stream-ordered, graph-capture legal)
  u32* bbx = (u32*)ws + 4;
  hipMemsetAsync(bbx,     0xFF, 12, stream);          // min slots
  hipMemsetAsync(bbx + 3, 0x00, 12, stream);          // max slots
  hipMemsetAsync(counts,  0x00, GR3 * sizeof(int), stream);

  setup_kernel<<<n/256 + 7, 256, 0, stream>>>(
      d_in[0], d_in[1], wa, ca, flag, pos4, h0, n);

  hist_kernel<<<n/256, 256, 0, stream>>>(pos4, bbx, counts, cid, n);
  scan_kernel<<<1, 1024, 0, stream>>>(counts, cellstart, cursor);
  scatter_kernel<<<n/256, 256, 0, stream>>>(pos4, cid, cursor, sidx, spos4, n);
  knn7_kernel<<<n/KNN7_WPB, 256, 0, stream>>>(spos4, sidx, cellstart,
                                              bbx, nbr, n);

  // <CIN, CMID, KT1, NT, KT2>
  conv_mfma7_kernel<6, 64, 1, 4, 2><<<n/8, 256, 0, stream>>>(
      h0, (const unsigned short*)nullptr, pos4, nbr, flag, wptr[0], wptr[1],
      vptr[0], vptr[1], vptr[2], vptr[3], h1b, d_out, (size_t)0);
  conv_mfma7_kernel<64, 64, 3, 4, 2><<<n/8, 256, 0, stream>>>(
      (const float*)nullptr, h1b, pos4, nbr, flag, wptr[2], wptr[3],
      vptr[4], vptr[5], vptr[6], vptr[7], h2b, d_out, (size_t)n*64);
  conv_mfma7_kernel<64, 128, 3, 8, 4><<<n/8, 256, 0, stream>>>(
      (const float*)nullptr, h2b, pos4, nbr, flag, wptr[4], wptr[5],
      vptr[8], vptr[9], vptr[10], vptr[11],
      (unsigned short*)nullptr, d_out, (size_t)n*128);
}